// Round 9
// baseline (283.051 us; speedup 1.0000x reference)
//
#include <hip/hip_runtime.h>
#include <hip/hip_bf16.h>

#define N_NODES 50000
#define N_EDGES 800000
#define IN_DIM  128
#define IN_CH   64
#define HIDDEN  64
#define OUT_CH  128
#define NUM_CLS 16
#define NUM_G   512
#define NBUK    ((N_NODES + 255) >> 8)    // 196 buckets of 256 dst nodes
#define BCAP    6144                      // mean 4082/bucket -> huge margin
#define EPB_A   4096                      // edges per pass-A block

typedef __attribute__((ext_vector_type(8))) short short8;
typedef __attribute__((ext_vector_type(4))) float f32x4;

__device__ inline float bits2f(unsigned short u) {
  unsigned x = (unsigned)u << 16;
  float f;
  __builtin_memcpy(&f, &x, 4);
  return f;
}
__device__ inline unsigned short f2bits(float v) {
  __hip_bfloat16 b = __float2bfloat16(v);   // RNE
  unsigned short s;
  __builtin_memcpy(&s, &b, 2);
  return s;
}
__device__ inline short8 zero8() {
  short8 z;
#pragma unroll
  for (int i = 0; i < 8; ++i) z[i] = 0;
  return z;
}
__device__ inline void acc2(float& a0, float& a1, unsigned v) {
  a0 += bits2f((unsigned short)v);
  a1 += bits2f((unsigned short)(v >> 16));
}
__device__ inline void accu4(float* a, uint4 v) {
  acc2(a[0], a[1], v.x); acc2(a[2], a[3], v.y);
  acc2(a[4], a[5], v.z); acc2(a[6], a[7], v.w);
}

// ============ stage1: one wave per 16 rows (3125 blocks for occupancy) ============
__global__ __launch_bounds__(64) void k_stage1(
    const float* __restrict__ Ap, const short* __restrict__ Wa,
    const float* __restrict__ bias, unsigned short* __restrict__ outp) {
  constexpr int DIN = 128, DOUT = 64, KT = DIN / 32, CT = DOUT / 16;
  const int lane = threadIdx.x;
  const int m = lane & 15;
  const int q = lane >> 4;
  const int row = blockIdx.x * 16 + m;
  const bool ok = row < N_NODES;

  short8 afr[KT];
#pragma unroll
  for (int kt = 0; kt < KT; ++kt) {
    short8 f = zero8();
    if (ok) {
      const float* ap = Ap + (size_t)row * DIN + kt * 32 + q * 8;
      float4 x0 = *(const float4*)ap;
      float4 x1 = *(const float4*)(ap + 4);
      f[0] = (short)f2bits(x0.x); f[1] = (short)f2bits(x0.y);
      f[2] = (short)f2bits(x0.z); f[3] = (short)f2bits(x0.w);
      f[4] = (short)f2bits(x1.x); f[5] = (short)f2bits(x1.y);
      f[6] = (short)f2bits(x1.z); f[7] = (short)f2bits(x1.w);
    }
    afr[kt] = f;
  }
  const int rbase = blockIdx.x * 16;
#pragma unroll
  for (int ct = 0; ct < CT; ++ct) {
    f32x4 c = {0.f, 0.f, 0.f, 0.f};
#pragma unroll
    for (int kt = 0; kt < KT; ++kt) {
      short8 b = *(const short8*)(Wa + ((size_t)(kt * CT + ct) * 64 + lane) * 8);
      c = __builtin_amdgcn_mfma_f32_16x16x32_bf16(afr[kt], b, c, 0, 0, 0);
    }
    float bv = bias[ct * 16 + m];
#pragma unroll
    for (int r = 0; r < 4; ++r) {
      int ro = rbase + q * 4 + r;
      if (ro < N_NODES) outp[(size_t)ro * DOUT + ct * 16 + m] = f2bits(c[r] + bv);
    }
  }
}

// ============ fused gather + dual MFMA, 4-way edge-split per block ============
// 256 thr = 4 waves, all covering the same 16 nodes. Wave w gathers edge
// quarter w into private fp32 fragments; waves 1-3 publish to LDS (transposed,
// conflict-free); wave 0 combines, converts, runs MFMA + store.
template <int DIN, int DOUT>
__global__ __launch_bounds__(256) void k_fused(
    const unsigned short* __restrict__ h, const int* __restrict__ esrc,
    const int* __restrict__ off, const short* __restrict__ Wa,
    const short* __restrict__ Wh, const float* __restrict__ bias,
    unsigned short* __restrict__ outp) {
  constexpr int KT = DIN / 32;
  constexpr int CT = DOUT / 16;
  constexpr int NE = KT * 8;               // fp32 partials per lane
  __shared__ float lsum[3 * NE * 64];

  const int tid = threadIdx.x;
  const int wave = tid >> 6;
  const int lane = tid & 63;
  const int m = lane & 15;
  const int q = lane >> 4;
  const int node = blockIdx.x * 16 + m;

  float acc[KT][8];
#pragma unroll
  for (int kt = 0; kt < KT; ++kt)
#pragma unroll
    for (int j = 0; j < 8; ++j) acc[kt][j] = 0.f;

  if (node < N_NODES) {
    int beg = off[node], len = off[node + 1] - beg;
    int e = beg + (len * wave) / 4;
    int end = beg + (len * (wave + 1)) / 4;
    const unsigned short* hq = h + q * 8;
    for (; e + 2 <= end; e += 2) {
      int s0 = esrc[e], s1 = esrc[e + 1];
      const unsigned short* r0 = hq + (size_t)s0 * DIN;
      const unsigned short* r1 = hq + (size_t)s1 * DIN;
#pragma unroll
      for (int kt = 0; kt < KT; ++kt) {
        uint4 va = *(const uint4*)(r0 + kt * 32);
        uint4 vb = *(const uint4*)(r1 + kt * 32);
        accu4(acc[kt], va);
        accu4(acc[kt], vb);
      }
    }
    if (e < end) {
      const unsigned short* r0 = hq + (size_t)esrc[e] * DIN;
#pragma unroll
      for (int kt = 0; kt < KT; ++kt)
        accu4(acc[kt], *(const uint4*)(r0 + kt * 32));
    }
  }

  if (wave > 0) {
    float* base = lsum + (size_t)(wave - 1) * NE * 64 + lane;
#pragma unroll
    for (int kt = 0; kt < KT; ++kt)
#pragma unroll
      for (int j = 0; j < 8; ++j) base[(kt * 8 + j) * 64] = acc[kt][j];
  }
  __syncthreads();
  if (wave != 0) return;

#pragma unroll
  for (int w = 0; w < 3; ++w) {
    const float* base = lsum + (size_t)w * NE * 64 + lane;
#pragma unroll
    for (int kt = 0; kt < KT; ++kt)
#pragma unroll
      for (int j = 0; j < 8; ++j) acc[kt][j] += base[(kt * 8 + j) * 64];
  }

  short8 afr[KT], hfr[KT];
#pragma unroll
  for (int kt = 0; kt < KT; ++kt) {
    short8 f;
#pragma unroll
    for (int j = 0; j < 8; ++j) f[j] = (short)f2bits(acc[kt][j]);
    afr[kt] = f;
    hfr[kt] = (node < N_NODES)
                  ? *(const short8*)(h + (size_t)node * DIN + kt * 32 + q * 8)
                  : zero8();
  }

  const int rbase = blockIdx.x * 16;
#pragma unroll
  for (int ct = 0; ct < CT; ++ct) {
    f32x4 c = {0.f, 0.f, 0.f, 0.f};
#pragma unroll
    for (int kt = 0; kt < KT; ++kt) {
      short8 b = *(const short8*)(Wa + ((size_t)(kt * CT + ct) * 64 + lane) * 8);
      c = __builtin_amdgcn_mfma_f32_16x16x32_bf16(afr[kt], b, c, 0, 0, 0);
      short8 bh = *(const short8*)(Wh + ((size_t)(kt * CT + ct) * 64 + lane) * 8);
      c = __builtin_amdgcn_mfma_f32_16x16x32_bf16(hfr[kt], bh, c, 0, 0, 0);
    }
    float bv = bias[ct * 16 + m];
#pragma unroll
    for (int r = 0; r < 4; ++r) {
      int row = rbase + q * 4 + r;
      if (row < N_NODES)
        outp[(size_t)row * DOUT + ct * 16 + m] = f2bits(fmaxf(c[r] + bv, 0.f));
    }
  }
}

// ============ weight pack (all 7 in one launch) ============
template <int DIN, int DOUT>
__device__ inline void pack1(const float* __restrict__ W, short* __restrict__ o,
                             int t) {
  constexpr int CT = DOUT / 16;
  int j = t & 7;
  int lane = (t >> 3) & 63;
  int kc = t >> 9;
  int ct = kc % CT;
  int kt = kc / CT;
  int k = kt * 32 + (lane >> 4) * 8 + j;
  int n = ct * 16 + (lane & 15);
  o[t] = (short)f2bits(W[k * DOUT + n]);
}

__global__ __launch_bounds__(256) void k_packall(
    const float* w1, const float* r1, const float* o1, const float* r2,
    const float* o2, const float* r3, const float* o3,
    short* w1p, short* r1p, short* o1p, short* r2p, short* o2p,
    short* r3p, short* o3p) {
  int b = blockIdx.x, t = threadIdx.x;
  if      (b < 32)  pack1<128, 64>(w1, w1p, (b - 0) * 256 + t);
  else if (b < 48)  pack1<64, 64>(r1, r1p, (b - 32) * 256 + t);
  else if (b < 64)  pack1<64, 64>(o1, o1p, (b - 48) * 256 + t);
  else if (b < 96)  pack1<64, 128>(r2, r2p, (b - 64) * 256 + t);
  else if (b < 128) pack1<64, 128>(o2, o2p, (b - 96) * 256 + t);
  else if (b < 192) pack1<128, 128>(r3, r3p, (b - 128) * 256 + t);
  else              pack1<128, 128>(o3, o3p, (b - 192) * 256 + t);
}

// ================= bucketed CSR build =================
__global__ __launch_bounds__(256) void k_bucketA(const int* __restrict__ src,
    const int* __restrict__ dst, int* __restrict__ bcnt, uint2* __restrict__ bbuf) {
  __shared__ int hist[NBUK], sbase[NBUK], lcur[NBUK];
  const int t = threadIdx.x;
  for (int i = t; i < NBUK; i += 256) { hist[i] = 0; lcur[i] = 0; }
  __syncthreads();
  const int e0 = blockIdx.x * EPB_A;
  int s_[16], d_[16];
  int cnt = 0;
#pragma unroll
  for (int k = 0; k < 16; ++k) {
    int e = e0 + k * 256 + t;
    if (e < N_EDGES) {
      s_[cnt] = src[e]; d_[cnt] = dst[e];
      atomicAdd(&hist[d_[cnt] >> 8], 1);
      cnt++;
    }
  }
  __syncthreads();
  for (int i = t; i < NBUK; i += 256) sbase[i] = atomicAdd(&bcnt[i], hist[i]);
  __syncthreads();
  for (int k = 0; k < cnt; ++k) {
    int b = d_[k] >> 8;
    int pos = sbase[b] + atomicAdd(&lcur[b], 1);
    if (pos < BCAP) bbuf[(size_t)b * BCAP + pos] = make_uint2((unsigned)s_[k], (unsigned)d_[k]);
  }
}

// exclusive scan of bucket counts -> bucket base offsets; writes off[N_NODES]
__global__ __launch_bounds__(256) void k_scanb(const int* __restrict__ bcnt,
    int* __restrict__ bbase, int* __restrict__ off) {
  __shared__ int s[256];
  int t = threadIdx.x;
  int v0 = (t < NBUK) ? min(bcnt[t], BCAP) : 0;
  s[t] = v0;
  __syncthreads();
  for (int st = 1; st < 256; st <<= 1) {
    int v = (t >= st) ? s[t - st] : 0;
    __syncthreads();
    s[t] += v;
    __syncthreads();
  }
  if (t < NBUK) bbase[t] = s[t] - v0;
  if (t == NBUK - 1) off[N_NODES] = s[t];
}

// per-bucket: degree hist + intra-bucket scan -> off[node]; then scatter esrc
__global__ __launch_bounds__(256) void k_bfin(const int* __restrict__ bcnt,
    const uint2* __restrict__ bbuf, const int* __restrict__ bbase,
    int* __restrict__ off, int* __restrict__ esrc) {
  __shared__ int cnt[256], s[256], soff[256];
  const int b = blockIdx.x;
  const int t = threadIdx.x;
  cnt[t] = 0;
  __syncthreads();
  int n = min(bcnt[b], BCAP);
  for (int i = t; i < n; i += 256)
    atomicAdd(&cnt[bbuf[(size_t)b * BCAP + i].y & 255], 1);
  __syncthreads();
  int v0 = cnt[t];
  s[t] = v0;
  __syncthreads();
  for (int st = 1; st < 256; st <<= 1) {
    int v = (t >= st) ? s[t - st] : 0;
    __syncthreads();
    s[t] += v;
    __syncthreads();
  }
  int myoff = bbase[b] + s[t] - v0;
  int node = b * 256 + t;
  if (node < N_NODES) off[node] = myoff;
  soff[t] = myoff;
  cnt[t] = 0;            // reuse as per-node cursor
  __syncthreads();
  for (int i = t; i < n; i += 256) {
    uint2 p = bbuf[(size_t)b * BCAP + i];
    int l = p.y & 255;
    int r = atomicAdd(&cnt[l], 1);
    esrc[soff[l] + r] = (int)p.x;
  }
}

// ================= fused pool + head =================
__device__ inline int lbound(const int* __restrict__ a, int n, int v) {
  int lo = 0, hi = n;
  while (lo < hi) {
    int m = (lo + hi) >> 1;
    if (a[m] < v) lo = m + 1; else hi = m;
  }
  return lo;
}

__global__ __launch_bounds__(128) void k_poolhead(const unsigned short* __restrict__ h3,
    const int* __restrict__ batch, const float* __restrict__ lw,
    const float* __restrict__ lb, float* __restrict__ out) {
  __shared__ float sp[128];
  int g = blockIdx.x;
  int t = threadIdx.x;
  int lo = lbound(batch, N_NODES, g);
  int hi = lbound(batch, N_NODES, g + 1);
  float a0 = 0.f, a1 = 0.f, a2 = 0.f, a3 = 0.f;
  int r = lo;
  for (; r + 4 <= hi; r += 4) {
    a0 += bits2f(h3[(size_t)(r + 0) * OUT_CH + t]);
    a1 += bits2f(h3[(size_t)(r + 1) * OUT_CH + t]);
    a2 += bits2f(h3[(size_t)(r + 2) * OUT_CH + t]);
    a3 += bits2f(h3[(size_t)(r + 3) * OUT_CH + t]);
  }
  for (; r < hi; ++r) a0 += bits2f(h3[(size_t)r * OUT_CH + t]);
  float inv = (hi > lo) ? 1.f / (float)(hi - lo) : 0.f;
  sp[t] = ((a0 + a1) + (a2 + a3)) * inv;
  __syncthreads();
  if (t < NUM_CLS) {
    float s = lb[t];
#pragma unroll
    for (int k = 0; k < OUT_CH; ++k) s = fmaf(sp[k], lw[k * NUM_CLS + t], s);
    out[g * NUM_CLS + t] = s;
  }
}

extern "C" void kernel_launch(void* const* d_in, const int* in_sizes, int n_in,
                              void* d_out, int out_size, void* d_ws, size_t ws_size,
                              hipStream_t stream) {
  const float* x      = (const float*)d_in[0];
  const int*   ei     = (const int*)d_in[1];
  const int*   batch  = (const int*)d_in[2];
  const float* w1     = (const float*)d_in[4];
  const float* b1     = (const float*)d_in[5];
  const float* rel1w  = (const float*)d_in[6];
  const float* rel1b  = (const float*)d_in[7];
  const float* root1w = (const float*)d_in[8];
  const float* rel2w  = (const float*)d_in[9];
  const float* rel2b  = (const float*)d_in[10];
  const float* root2w = (const float*)d_in[11];
  const float* rel3w  = (const float*)d_in[12];
  const float* rel3b  = (const float*)d_in[13];
  const float* root3w = (const float*)d_in[14];
  const float* linw   = (const float*)d_in[15];
  const float* linb   = (const float*)d_in[16];
  const int* src = ei;
  const int* dst = ei + N_EDGES;
  float* out = (float*)d_out;

  // ---- workspace layout ----
  unsigned short* P = (unsigned short*)d_ws;            // [N,128] bf16
  unsigned short* Q = P + (size_t)N_NODES * 128;        // [N,128] bf16
  unsigned short* R = Q + (size_t)N_NODES * 128;        // [N,128] bf16
  short* WP = (short*)(R + (size_t)N_NODES * 128);
  short* w1p  = WP;                 // 128x64
  short* r1p  = w1p + 8192;         // 64x64
  short* o1p  = r1p + 4096;         // 64x64
  short* r2p  = o1p + 4096;         // 64x128
  short* o2p  = r2p + 8192;         // 64x128
  short* r3p  = o2p + 8192;         // 128x128
  short* o3p  = r3p + 16384;        // 128x128
  int* off     = (int*)(o3p + 16384);                   // N+1
  int* bcnt    = off + (N_NODES + 1);                   // NBUK
  int* bbase   = bcnt + NBUK;                           // NBUK
  int* esrc    = bbase + NBUK + 2;                      // [E]
  uint2* bbuf  = (uint2*)((char*)(esrc + N_EDGES) +
                          ((16 - (((size_t)(esrc + N_EDGES)) & 15)) & 15));

  // ---- bucketed CSR build (4 dispatches incl. memset) ----
  hipMemsetAsync(bcnt, 0, NBUK * sizeof(int), stream);
  k_bucketA<<<(N_EDGES + EPB_A - 1) / EPB_A, 256, 0, stream>>>(src, dst, bcnt, bbuf);
  k_scanb<<<1, 256, 0, stream>>>(bcnt, bbase, off);
  k_bfin<<<NBUK, 256, 0, stream>>>(bcnt, bbuf, bbase, off, esrc);

  // ---- weights ----
  k_packall<<<256, 256, 0, stream>>>(w1, rel1w, root1w, rel2w, root2w, rel3w,
                                     root3w, w1p, r1p, o1p, r2p, o2p, r3p, o3p);

  const int GF = (N_NODES + 15) / 16;     // 3125 blocks, 16 nodes each

  // ---- pipeline ----
  k_stage1<<<GF, 64, 0, stream>>>(x, w1p, b1, P);
  k_fused<64, 64><<<GF, 256, 0, stream>>>(P, esrc, off, r1p, o1p, rel1b, R);
  k_fused<64, 128><<<GF, 256, 0, stream>>>(R, esrc, off, r2p, o2p, rel2b, Q);
  k_fused<128, 128><<<GF, 256, 0, stream>>>(Q, esrc, off, r3p, o3p, rel3b, P);
  k_poolhead<<<NUM_G, 128, 0, stream>>>(P, batch, linw, linb, out);
}

// Round 10
// 264.288 us; speedup vs baseline: 1.0710x; 1.0710x over previous
//
#include <hip/hip_runtime.h>
#include <hip/hip_bf16.h>

#define N_NODES 50000
#define N_EDGES 800000
#define IN_DIM  128
#define IN_CH   64
#define HIDDEN  64
#define OUT_CH  128
#define NUM_CLS 16
#define NUM_G   512
#define NBUK    ((N_NODES + 255) >> 8)    // 196 buckets of 256 dst nodes
#define BCAP    6144                      // mean 4082/bucket -> huge margin
#define EPB_A   4096                      // edges per pass-A block

typedef __attribute__((ext_vector_type(8))) short short8;
typedef __attribute__((ext_vector_type(4))) float f32x4;

__device__ inline float bits2f(unsigned short u) {
  unsigned x = (unsigned)u << 16;
  float f;
  __builtin_memcpy(&f, &x, 4);
  return f;
}
__device__ inline unsigned short f2bits(float v) {
  __hip_bfloat16 b = __float2bfloat16(v);   // RNE
  unsigned short s;
  __builtin_memcpy(&s, &b, 2);
  return s;
}
__device__ inline short8 zero8() {
  short8 z;
#pragma unroll
  for (int i = 0; i < 8; ++i) z[i] = 0;
  return z;
}
__device__ inline void acc2(float& a0, float& a1, unsigned v) {
  a0 += bits2f((unsigned short)v);
  a1 += bits2f((unsigned short)(v >> 16));
}
__device__ inline void accu4(float* a, uint4 v) {
  acc2(a[0], a[1], v.x); acc2(a[2], a[3], v.y);
  acc2(a[4], a[5], v.z); acc2(a[6], a[7], v.w);
}

// ============ stage1: one wave per 16 rows ============
__global__ __launch_bounds__(64) void k_stage1(
    const float* __restrict__ Ap, const short* __restrict__ Wa,
    const float* __restrict__ bias, unsigned short* __restrict__ outp) {
  constexpr int DIN = 128, DOUT = 64, KT = DIN / 32, CT = DOUT / 16;
  const int lane = threadIdx.x;
  const int m = lane & 15;
  const int q = lane >> 4;
  const int row = blockIdx.x * 16 + m;
  const bool ok = row < N_NODES;

  short8 afr[KT];
#pragma unroll
  for (int kt = 0; kt < KT; ++kt) {
    short8 f = zero8();
    if (ok) {
      const float* ap = Ap + (size_t)row * DIN + kt * 32 + q * 8;
      float4 x0 = *(const float4*)ap;
      float4 x1 = *(const float4*)(ap + 4);
      f[0] = (short)f2bits(x0.x); f[1] = (short)f2bits(x0.y);
      f[2] = (short)f2bits(x0.z); f[3] = (short)f2bits(x0.w);
      f[4] = (short)f2bits(x1.x); f[5] = (short)f2bits(x1.y);
      f[6] = (short)f2bits(x1.z); f[7] = (short)f2bits(x1.w);
    }
    afr[kt] = f;
  }
  const int rbase = blockIdx.x * 16;
#pragma unroll
  for (int ct = 0; ct < CT; ++ct) {
    f32x4 c = {0.f, 0.f, 0.f, 0.f};
#pragma unroll
    for (int kt = 0; kt < KT; ++kt) {
      short8 b = *(const short8*)(Wa + ((size_t)(kt * CT + ct) * 64 + lane) * 8);
      c = __builtin_amdgcn_mfma_f32_16x16x32_bf16(afr[kt], b, c, 0, 0, 0);
    }
    float bv = bias[ct * 16 + m];
#pragma unroll
    for (int r = 0; r < 4; ++r) {
      int ro = rbase + q * 4 + r;
      if (ro < N_NODES) outp[(size_t)ro * DOUT + ct * 16 + m] = f2bits(c[r] + bv);
    }
  }
}

// ============ fused gather + dual MFMA, one wave per 16 nodes ============
// MLP-limited kernel: UN-edge unrolled gather keeps UN*KT uint4 loads in
// flight per lane (16 for both layer shapes). Loads batched before
// accumulation so they issue back-to-back.
template <int DIN, int DOUT, int UN>
__global__ __launch_bounds__(64) void k_fused(
    const unsigned short* __restrict__ h, const int* __restrict__ esrc,
    const int* __restrict__ off, const short* __restrict__ Wa,
    const short* __restrict__ Wh, const float* __restrict__ bias,
    unsigned short* __restrict__ outp) {
  constexpr int KT = DIN / 32;
  constexpr int CT = DOUT / 16;
  const int lane = threadIdx.x;
  const int m = lane & 15;
  const int q = lane >> 4;
  const int node = blockIdx.x * 16 + m;
  const bool ok = node < N_NODES;

  // root-row fragments first: in flight during the gather
  short8 hfr[KT];
#pragma unroll
  for (int kt = 0; kt < KT; ++kt)
    hfr[kt] = ok ? *(const short8*)(h + (size_t)node * DIN + kt * 32 + q * 8)
                 : zero8();

  float acc[KT][8];
#pragma unroll
  for (int kt = 0; kt < KT; ++kt)
#pragma unroll
    for (int j = 0; j < 8; ++j) acc[kt][j] = 0.f;

  if (ok) {
    int e = off[node], end = off[node + 1];
    const unsigned short* hq = h + q * 8;
    int sv[UN];
    uint4 tv[UN][KT];
    for (; e + UN <= end; e += UN) {
#pragma unroll
      for (int u = 0; u < UN; ++u) sv[u] = esrc[e + u];
#pragma unroll
      for (int u = 0; u < UN; ++u) {
        const unsigned short* r0 = hq + (size_t)sv[u] * DIN;
#pragma unroll
        for (int kt = 0; kt < KT; ++kt)
          tv[u][kt] = *(const uint4*)(r0 + kt * 32);
      }
#pragma unroll
      for (int u = 0; u < UN; ++u)
#pragma unroll
        for (int kt = 0; kt < KT; ++kt) accu4(acc[kt], tv[u][kt]);
    }
    for (; e < end; ++e) {
      const unsigned short* r0 = hq + (size_t)esrc[e] * DIN;
#pragma unroll
      for (int kt = 0; kt < KT; ++kt)
        accu4(acc[kt], *(const uint4*)(r0 + kt * 32));
    }
  }

  short8 afr[KT];
#pragma unroll
  for (int kt = 0; kt < KT; ++kt) {
    short8 f;
#pragma unroll
    for (int j = 0; j < 8; ++j) f[j] = (short)f2bits(acc[kt][j]);
    afr[kt] = f;
  }

  const int rbase = blockIdx.x * 16;
#pragma unroll
  for (int ct = 0; ct < CT; ++ct) {
    f32x4 c = {0.f, 0.f, 0.f, 0.f};
#pragma unroll
    for (int kt = 0; kt < KT; ++kt) {
      short8 b = *(const short8*)(Wa + ((size_t)(kt * CT + ct) * 64 + lane) * 8);
      c = __builtin_amdgcn_mfma_f32_16x16x32_bf16(afr[kt], b, c, 0, 0, 0);
      short8 bh = *(const short8*)(Wh + ((size_t)(kt * CT + ct) * 64 + lane) * 8);
      c = __builtin_amdgcn_mfma_f32_16x16x32_bf16(hfr[kt], bh, c, 0, 0, 0);
    }
    float bv = bias[ct * 16 + m];
#pragma unroll
    for (int r = 0; r < 4; ++r) {
      int row = rbase + q * 4 + r;
      if (row < N_NODES)
        outp[(size_t)row * DOUT + ct * 16 + m] = f2bits(fmaxf(c[r] + bv, 0.f));
    }
  }
}

// ============ weight pack (all 7 in one launch) ============
template <int DIN, int DOUT>
__device__ inline void pack1(const float* __restrict__ W, short* __restrict__ o,
                             int t) {
  constexpr int CT = DOUT / 16;
  int j = t & 7;
  int lane = (t >> 3) & 63;
  int kc = t >> 9;
  int ct = kc % CT;
  int kt = kc / CT;
  int k = kt * 32 + (lane >> 4) * 8 + j;
  int n = ct * 16 + (lane & 15);
  o[t] = (short)f2bits(W[k * DOUT + n]);
}

__global__ __launch_bounds__(256) void k_packall(
    const float* w1, const float* r1, const float* o1, const float* r2,
    const float* o2, const float* r3, const float* o3,
    short* w1p, short* r1p, short* o1p, short* r2p, short* o2p,
    short* r3p, short* o3p) {
  int b = blockIdx.x, t = threadIdx.x;
  if      (b < 32)  pack1<128, 64>(w1, w1p, (b - 0) * 256 + t);
  else if (b < 48)  pack1<64, 64>(r1, r1p, (b - 32) * 256 + t);
  else if (b < 64)  pack1<64, 64>(o1, o1p, (b - 48) * 256 + t);
  else if (b < 96)  pack1<64, 128>(r2, r2p, (b - 64) * 256 + t);
  else if (b < 128) pack1<64, 128>(o2, o2p, (b - 96) * 256 + t);
  else if (b < 192) pack1<128, 128>(r3, r3p, (b - 128) * 256 + t);
  else              pack1<128, 128>(o3, o3p, (b - 192) * 256 + t);
}

// ================= bucketed CSR build =================
__global__ __launch_bounds__(256) void k_bucketA(const int* __restrict__ src,
    const int* __restrict__ dst, int* __restrict__ bcnt, uint2* __restrict__ bbuf) {
  __shared__ int hist[NBUK], sbase[NBUK], lcur[NBUK];
  const int t = threadIdx.x;
  for (int i = t; i < NBUK; i += 256) { hist[i] = 0; lcur[i] = 0; }
  __syncthreads();
  const int e0 = blockIdx.x * EPB_A;
  int s_[16], d_[16];
  int cnt = 0;
#pragma unroll
  for (int k = 0; k < 16; ++k) {
    int e = e0 + k * 256 + t;
    if (e < N_EDGES) {
      s_[cnt] = src[e]; d_[cnt] = dst[e];
      atomicAdd(&hist[d_[cnt] >> 8], 1);
      cnt++;
    }
  }
  __syncthreads();
  for (int i = t; i < NBUK; i += 256) sbase[i] = atomicAdd(&bcnt[i], hist[i]);
  __syncthreads();
  for (int k = 0; k < cnt; ++k) {
    int b = d_[k] >> 8;
    int pos = sbase[b] + atomicAdd(&lcur[b], 1);
    if (pos < BCAP) bbuf[(size_t)b * BCAP + pos] = make_uint2((unsigned)s_[k], (unsigned)d_[k]);
  }
}

// exclusive scan of bucket counts -> bucket base offsets; writes off[N_NODES]
__global__ __launch_bounds__(256) void k_scanb(const int* __restrict__ bcnt,
    int* __restrict__ bbase, int* __restrict__ off) {
  __shared__ int s[256];
  int t = threadIdx.x;
  int v0 = (t < NBUK) ? min(bcnt[t], BCAP) : 0;
  s[t] = v0;
  __syncthreads();
  for (int st = 1; st < 256; st <<= 1) {
    int v = (t >= st) ? s[t - st] : 0;
    __syncthreads();
    s[t] += v;
    __syncthreads();
  }
  if (t < NBUK) bbase[t] = s[t] - v0;
  if (t == NBUK - 1) off[N_NODES] = s[t];
}

// per-bucket: degree hist + intra-bucket scan -> off[node]; then scatter esrc
__global__ __launch_bounds__(256) void k_bfin(const int* __restrict__ bcnt,
    const uint2* __restrict__ bbuf, const int* __restrict__ bbase,
    int* __restrict__ off, int* __restrict__ esrc) {
  __shared__ int cnt[256], s[256], soff[256];
  const int b = blockIdx.x;
  const int t = threadIdx.x;
  cnt[t] = 0;
  __syncthreads();
  int n = min(bcnt[b], BCAP);
  for (int i = t; i < n; i += 256)
    atomicAdd(&cnt[bbuf[(size_t)b * BCAP + i].y & 255], 1);
  __syncthreads();
  int v0 = cnt[t];
  s[t] = v0;
  __syncthreads();
  for (int st = 1; st < 256; st <<= 1) {
    int v = (t >= st) ? s[t - st] : 0;
    __syncthreads();
    s[t] += v;
    __syncthreads();
  }
  int myoff = bbase[b] + s[t] - v0;
  int node = b * 256 + t;
  if (node < N_NODES) off[node] = myoff;
  soff[t] = myoff;
  cnt[t] = 0;            // reuse as per-node cursor
  __syncthreads();
  for (int i = t; i < n; i += 256) {
    uint2 p = bbuf[(size_t)b * BCAP + i];
    int l = p.y & 255;
    int r = atomicAdd(&cnt[l], 1);
    esrc[soff[l] + r] = (int)p.x;
  }
}

// ================= fused pool + head =================
__device__ inline int lbound(const int* __restrict__ a, int n, int v) {
  int lo = 0, hi = n;
  while (lo < hi) {
    int m = (lo + hi) >> 1;
    if (a[m] < v) lo = m + 1; else hi = m;
  }
  return lo;
}

__global__ __launch_bounds__(128) void k_poolhead(const unsigned short* __restrict__ h3,
    const int* __restrict__ batch, const float* __restrict__ lw,
    const float* __restrict__ lb, float* __restrict__ out) {
  __shared__ float sp[128];
  int g = blockIdx.x;
  int t = threadIdx.x;
  int lo = lbound(batch, N_NODES, g);
  int hi = lbound(batch, N_NODES, g + 1);
  float a0 = 0.f, a1 = 0.f, a2 = 0.f, a3 = 0.f;
  int r = lo;
  for (; r + 4 <= hi; r += 4) {
    a0 += bits2f(h3[(size_t)(r + 0) * OUT_CH + t]);
    a1 += bits2f(h3[(size_t)(r + 1) * OUT_CH + t]);
    a2 += bits2f(h3[(size_t)(r + 2) * OUT_CH + t]);
    a3 += bits2f(h3[(size_t)(r + 3) * OUT_CH + t]);
  }
  for (; r < hi; ++r) a0 += bits2f(h3[(size_t)r * OUT_CH + t]);
  float inv = (hi > lo) ? 1.f / (float)(hi - lo) : 0.f;
  sp[t] = ((a0 + a1) + (a2 + a3)) * inv;
  __syncthreads();
  if (t < NUM_CLS) {
    float s = lb[t];
#pragma unroll
    for (int k = 0; k < OUT_CH; ++k) s = fmaf(sp[k], lw[k * NUM_CLS + t], s);
    out[g * NUM_CLS + t] = s;
  }
}

extern "C" void kernel_launch(void* const* d_in, const int* in_sizes, int n_in,
                              void* d_out, int out_size, void* d_ws, size_t ws_size,
                              hipStream_t stream) {
  const float* x      = (const float*)d_in[0];
  const int*   ei     = (const int*)d_in[1];
  const int*   batch  = (const int*)d_in[2];
  const float* w1     = (const float*)d_in[4];
  const float* b1     = (const float*)d_in[5];
  const float* rel1w  = (const float*)d_in[6];
  const float* rel1b  = (const float*)d_in[7];
  const float* root1w = (const float*)d_in[8];
  const float* rel2w  = (const float*)d_in[9];
  const float* rel2b  = (const float*)d_in[10];
  const float* root2w = (const float*)d_in[11];
  const float* rel3w  = (const float*)d_in[12];
  const float* rel3b  = (const float*)d_in[13];
  const float* root3w = (const float*)d_in[14];
  const float* linw   = (const float*)d_in[15];
  const float* linb   = (const float*)d_in[16];
  const int* src = ei;
  const int* dst = ei + N_EDGES;
  float* out = (float*)d_out;

  // ---- workspace layout ----
  unsigned short* P = (unsigned short*)d_ws;            // [N,128] bf16
  unsigned short* Q = P + (size_t)N_NODES * 128;        // [N,128] bf16
  unsigned short* R = Q + (size_t)N_NODES * 128;        // [N,128] bf16
  short* WP = (short*)(R + (size_t)N_NODES * 128);
  short* w1p  = WP;                 // 128x64
  short* r1p  = w1p + 8192;         // 64x64
  short* o1p  = r1p + 4096;         // 64x64
  short* r2p  = o1p + 4096;         // 64x128
  short* o2p  = r2p + 8192;         // 64x128
  short* r3p  = o2p + 8192;         // 128x128
  short* o3p  = r3p + 16384;        // 128x128
  int* off     = (int*)(o3p + 16384);                   // N+1
  int* bcnt    = off + (N_NODES + 1);                   // NBUK
  int* bbase   = bcnt + NBUK;                           // NBUK
  int* esrc    = bbase + NBUK + 2;                      // [E]
  uint2* bbuf  = (uint2*)((char*)(esrc + N_EDGES) +
                          ((16 - (((size_t)(esrc + N_EDGES)) & 15)) & 15));

  // ---- bucketed CSR build ----
  hipMemsetAsync(bcnt, 0, NBUK * sizeof(int), stream);
  k_bucketA<<<(N_EDGES + EPB_A - 1) / EPB_A, 256, 0, stream>>>(src, dst, bcnt, bbuf);
  k_scanb<<<1, 256, 0, stream>>>(bcnt, bbase, off);
  k_bfin<<<NBUK, 256, 0, stream>>>(bcnt, bbuf, bbase, off, esrc);

  // ---- weights ----
  k_packall<<<256, 256, 0, stream>>>(w1, rel1w, root1w, rel2w, root2w, rel3w,
                                     root3w, w1p, r1p, o1p, r2p, o2p, r3p, o3p);

  const int GF = (N_NODES + 15) / 16;     // 3125 blocks, 16 nodes / 1 wave each

  // ---- pipeline ----
  k_stage1<<<GF, 64, 0, stream>>>(x, w1p, b1, P);
  k_fused<64, 64, 8><<<GF, 64, 0, stream>>>(P, esrc, off, r1p, o1p, rel1b, R);
  k_fused<64, 128, 8><<<GF, 64, 0, stream>>>(R, esrc, off, r2p, o2p, rel2b, Q);
  k_fused<128, 128, 4><<<GF, 64, 0, stream>>>(Q, esrc, off, r3p, o3p, rel3b, P);
  k_poolhead<<<NUM_G, 128, 0, stream>>>(P, batch, linw, linb, out);
}

// Round 11
// 254.759 us; speedup vs baseline: 1.1111x; 1.0374x over previous
//
#include <hip/hip_runtime.h>
#include <hip/hip_bf16.h>

#define N_NODES 50000
#define N_EDGES 800000
#define IN_DIM  128
#define IN_CH   64
#define HIDDEN  64
#define OUT_CH  128
#define NUM_CLS 16
#define NUM_G   512
#define NBUK    ((N_NODES + 255) >> 8)    // 196 buckets of 256 dst nodes
#define BCAP    6144                      // mean 4082/bucket -> huge margin
#define EPB_A   4096                      // edges per pass-A block

typedef __attribute__((ext_vector_type(8))) short short8;
typedef __attribute__((ext_vector_type(4))) float f32x4;

__device__ inline float bits2f(unsigned short u) {
  unsigned x = (unsigned)u << 16;
  float f;
  __builtin_memcpy(&f, &x, 4);
  return f;
}
__device__ inline unsigned short f2bits(float v) {
  __hip_bfloat16 b = __float2bfloat16(v);   // RNE
  unsigned short s;
  __builtin_memcpy(&s, &b, 2);
  return s;
}
__device__ inline short8 zero8() {
  short8 z;
#pragma unroll
  for (int i = 0; i < 8; ++i) z[i] = 0;
  return z;
}
__device__ inline void acc2(float& a0, float& a1, unsigned v) {
  a0 += bits2f((unsigned short)v);
  a1 += bits2f((unsigned short)(v >> 16));
}
__device__ inline void accu4(float* a, uint4 v) {
  acc2(a[0], a[1], v.x); acc2(a[2], a[3], v.y);
  acc2(a[4], a[5], v.z); acc2(a[6], a[7], v.w);
}

// ============ stage1: one wave per 16 rows ============
__global__ __launch_bounds__(64) void k_stage1(
    const float* __restrict__ Ap, const short* __restrict__ Wa,
    const float* __restrict__ bias, unsigned short* __restrict__ outp) {
  constexpr int DIN = 128, DOUT = 64, KT = DIN / 32, CT = DOUT / 16;
  const int lane = threadIdx.x;
  const int m = lane & 15;
  const int q = lane >> 4;
  const int row = blockIdx.x * 16 + m;
  const bool ok = row < N_NODES;

  short8 afr[KT];
#pragma unroll
  for (int kt = 0; kt < KT; ++kt) {
    short8 f = zero8();
    if (ok) {
      const float* ap = Ap + (size_t)row * DIN + kt * 32 + q * 8;
      float4 x0 = *(const float4*)ap;
      float4 x1 = *(const float4*)(ap + 4);
      f[0] = (short)f2bits(x0.x); f[1] = (short)f2bits(x0.y);
      f[2] = (short)f2bits(x0.z); f[3] = (short)f2bits(x0.w);
      f[4] = (short)f2bits(x1.x); f[5] = (short)f2bits(x1.y);
      f[6] = (short)f2bits(x1.z); f[7] = (short)f2bits(x1.w);
    }
    afr[kt] = f;
  }
  const int rbase = blockIdx.x * 16;
#pragma unroll
  for (int ct = 0; ct < CT; ++ct) {
    f32x4 c = {0.f, 0.f, 0.f, 0.f};
#pragma unroll
    for (int kt = 0; kt < KT; ++kt) {
      short8 b = *(const short8*)(Wa + ((size_t)(kt * CT + ct) * 64 + lane) * 8);
      c = __builtin_amdgcn_mfma_f32_16x16x32_bf16(afr[kt], b, c, 0, 0, 0);
    }
    float bv = bias[ct * 16 + m];
#pragma unroll
    for (int r = 0; r < 4; ++r) {
      int ro = rbase + q * 4 + r;
      if (ro < N_NODES) outp[(size_t)ro * DOUT + ct * 16 + m] = f2bits(c[r] + bv);
    }
  }
}

// ============ fused gather + dual MFMA, one wave per 16 nodes ============
// R8-proven interleaved 2-edge loop: compiler software-pipelines the loads
// (8 uint4 in flight/lane) without forced vmcnt drains. Do not batch loads
// manually (R10 regression: occupancy 25->15%, BW -22%).
template <int DIN, int DOUT>
__global__ __launch_bounds__(64) void k_fused(
    const unsigned short* __restrict__ h, const int* __restrict__ esrc,
    const int* __restrict__ off, const short* __restrict__ Wa,
    const short* __restrict__ Wh, const float* __restrict__ bias,
    unsigned short* __restrict__ outp) {
  constexpr int KT = DIN / 32;
  constexpr int CT = DOUT / 16;
  const int lane = threadIdx.x;
  const int m = lane & 15;
  const int q = lane >> 4;
  const int node = blockIdx.x * 16 + m;
  const bool ok = node < N_NODES;

  float acc[KT][8];
#pragma unroll
  for (int kt = 0; kt < KT; ++kt)
#pragma unroll
    for (int j = 0; j < 8; ++j) acc[kt][j] = 0.f;

  if (ok) {
    int e = off[node], end = off[node + 1];
    const unsigned short* hq = h + q * 8;
    for (; e + 2 <= end; e += 2) {
      int s0 = esrc[e], s1 = esrc[e + 1];
      const unsigned short* r0 = hq + (size_t)s0 * DIN;
      const unsigned short* r1 = hq + (size_t)s1 * DIN;
#pragma unroll
      for (int kt = 0; kt < KT; ++kt) {
        uint4 va = *(const uint4*)(r0 + kt * 32);
        uint4 vb = *(const uint4*)(r1 + kt * 32);
        accu4(acc[kt], va);
        accu4(acc[kt], vb);
      }
    }
    if (e < end) {
      const unsigned short* r0 = hq + (size_t)esrc[e] * DIN;
#pragma unroll
      for (int kt = 0; kt < KT; ++kt)
        accu4(acc[kt], *(const uint4*)(r0 + kt * 32));
    }
  }

  short8 afr[KT], hfr[KT];
#pragma unroll
  for (int kt = 0; kt < KT; ++kt) {
    short8 f;
#pragma unroll
    for (int j = 0; j < 8; ++j) f[j] = (short)f2bits(acc[kt][j]);
    afr[kt] = f;
    hfr[kt] = ok ? *(const short8*)(h + (size_t)node * DIN + kt * 32 + q * 8)
                 : zero8();
  }

  const int rbase = blockIdx.x * 16;
#pragma unroll
  for (int ct = 0; ct < CT; ++ct) {
    f32x4 c = {0.f, 0.f, 0.f, 0.f};
#pragma unroll
    for (int kt = 0; kt < KT; ++kt) {
      short8 b = *(const short8*)(Wa + ((size_t)(kt * CT + ct) * 64 + lane) * 8);
      c = __builtin_amdgcn_mfma_f32_16x16x32_bf16(afr[kt], b, c, 0, 0, 0);
      short8 bh = *(const short8*)(Wh + ((size_t)(kt * CT + ct) * 64 + lane) * 8);
      c = __builtin_amdgcn_mfma_f32_16x16x32_bf16(hfr[kt], bh, c, 0, 0, 0);
    }
    float bv = bias[ct * 16 + m];
#pragma unroll
    for (int r = 0; r < 4; ++r) {
      int row = rbase + q * 4 + r;
      if (row < N_NODES)
        outp[(size_t)row * DOUT + ct * 16 + m] = f2bits(fmaxf(c[r] + bv, 0.f));
    }
  }
}

// ============ weight pack (all 7 in one launch) ============
template <int DIN, int DOUT>
__device__ inline void pack1(const float* __restrict__ W, short* __restrict__ o,
                             int t) {
  constexpr int CT = DOUT / 16;
  int j = t & 7;
  int lane = (t >> 3) & 63;
  int kc = t >> 9;
  int ct = kc % CT;
  int kt = kc / CT;
  int k = kt * 32 + (lane >> 4) * 8 + j;
  int n = ct * 16 + (lane & 15);
  o[t] = (short)f2bits(W[k * DOUT + n]);
}

__global__ __launch_bounds__(256) void k_packall(
    const float* w1, const float* r1, const float* o1, const float* r2,
    const float* o2, const float* r3, const float* o3,
    short* w1p, short* r1p, short* o1p, short* r2p, short* o2p,
    short* r3p, short* o3p) {
  int b = blockIdx.x, t = threadIdx.x;
  if      (b < 32)  pack1<128, 64>(w1, w1p, (b - 0) * 256 + t);
  else if (b < 48)  pack1<64, 64>(r1, r1p, (b - 32) * 256 + t);
  else if (b < 64)  pack1<64, 64>(o1, o1p, (b - 48) * 256 + t);
  else if (b < 96)  pack1<64, 128>(r2, r2p, (b - 64) * 256 + t);
  else if (b < 128) pack1<64, 128>(o2, o2p, (b - 96) * 256 + t);
  else if (b < 192) pack1<128, 128>(r3, r3p, (b - 128) * 256 + t);
  else              pack1<128, 128>(o3, o3p, (b - 192) * 256 + t);
}

// ================= bucketed CSR build =================
__global__ __launch_bounds__(256) void k_bucketA(const int* __restrict__ src,
    const int* __restrict__ dst, int* __restrict__ bcnt, uint2* __restrict__ bbuf) {
  __shared__ int hist[NBUK], sbase[NBUK], lcur[NBUK];
  const int t = threadIdx.x;
  for (int i = t; i < NBUK; i += 256) { hist[i] = 0; lcur[i] = 0; }
  __syncthreads();
  const int e0 = blockIdx.x * EPB_A;
  int s_[16], d_[16];
  int cnt = 0;
#pragma unroll
  for (int k = 0; k < 16; ++k) {
    int e = e0 + k * 256 + t;
    if (e < N_EDGES) {
      s_[cnt] = src[e]; d_[cnt] = dst[e];
      atomicAdd(&hist[d_[cnt] >> 8], 1);
      cnt++;
    }
  }
  __syncthreads();
  for (int i = t; i < NBUK; i += 256) sbase[i] = atomicAdd(&bcnt[i], hist[i]);
  __syncthreads();
  for (int k = 0; k < cnt; ++k) {
    int b = d_[k] >> 8;
    int pos = sbase[b] + atomicAdd(&lcur[b], 1);
    if (pos < BCAP) bbuf[(size_t)b * BCAP + pos] = make_uint2((unsigned)s_[k], (unsigned)d_[k]);
  }
}

// exclusive scan of bucket counts -> bucket base offsets; writes off[N_NODES]
__global__ __launch_bounds__(256) void k_scanb(const int* __restrict__ bcnt,
    int* __restrict__ bbase, int* __restrict__ off) {
  __shared__ int s[256];
  int t = threadIdx.x;
  int v0 = (t < NBUK) ? min(bcnt[t], BCAP) : 0;
  s[t] = v0;
  __syncthreads();
  for (int st = 1; st < 256; st <<= 1) {
    int v = (t >= st) ? s[t - st] : 0;
    __syncthreads();
    s[t] += v;
    __syncthreads();
  }
  if (t < NBUK) bbase[t] = s[t] - v0;
  if (t == NBUK - 1) off[N_NODES] = s[t];
}

// per-bucket: degree hist + intra-bucket scan -> off[node]; then scatter esrc
__global__ __launch_bounds__(256) void k_bfin(const int* __restrict__ bcnt,
    const uint2* __restrict__ bbuf, const int* __restrict__ bbase,
    int* __restrict__ off, int* __restrict__ esrc) {
  __shared__ int cnt[256], s[256], soff[256];
  const int b = blockIdx.x;
  const int t = threadIdx.x;
  cnt[t] = 0;
  __syncthreads();
  int n = min(bcnt[b], BCAP);
  for (int i = t; i < n; i += 256)
    atomicAdd(&cnt[bbuf[(size_t)b * BCAP + i].y & 255], 1);
  __syncthreads();
  int v0 = cnt[t];
  s[t] = v0;
  __syncthreads();
  for (int st = 1; st < 256; st <<= 1) {
    int v = (t >= st) ? s[t - st] : 0;
    __syncthreads();
    s[t] += v;
    __syncthreads();
  }
  int myoff = bbase[b] + s[t] - v0;
  int node = b * 256 + t;
  if (node < N_NODES) off[node] = myoff;
  soff[t] = myoff;
  cnt[t] = 0;            // reuse as per-node cursor
  __syncthreads();
  for (int i = t; i < n; i += 256) {
    uint2 p = bbuf[(size_t)b * BCAP + i];
    int l = p.y & 255;
    int r = atomicAdd(&cnt[l], 1);
    esrc[soff[l] + r] = (int)p.x;
  }
}

// ================= fused pool + head =================
__device__ inline int lbound(const int* __restrict__ a, int n, int v) {
  int lo = 0, hi = n;
  while (lo < hi) {
    int m = (lo + hi) >> 1;
    if (a[m] < v) lo = m + 1; else hi = m;
  }
  return lo;
}

__global__ __launch_bounds__(128) void k_poolhead(const unsigned short* __restrict__ h3,
    const int* __restrict__ batch, const float* __restrict__ lw,
    const float* __restrict__ lb, float* __restrict__ out) {
  __shared__ float sp[128];
  int g = blockIdx.x;
  int t = threadIdx.x;
  int lo = lbound(batch, N_NODES, g);
  int hi = lbound(batch, N_NODES, g + 1);
  float a0 = 0.f, a1 = 0.f, a2 = 0.f, a3 = 0.f;
  int r = lo;
  for (; r + 4 <= hi; r += 4) {
    a0 += bits2f(h3[(size_t)(r + 0) * OUT_CH + t]);
    a1 += bits2f(h3[(size_t)(r + 1) * OUT_CH + t]);
    a2 += bits2f(h3[(size_t)(r + 2) * OUT_CH + t]);
    a3 += bits2f(h3[(size_t)(r + 3) * OUT_CH + t]);
  }
  for (; r < hi; ++r) a0 += bits2f(h3[(size_t)r * OUT_CH + t]);
  float inv = (hi > lo) ? 1.f / (float)(hi - lo) : 0.f;
  sp[t] = ((a0 + a1) + (a2 + a3)) * inv;
  __syncthreads();
  if (t < NUM_CLS) {
    float s = lb[t];
#pragma unroll
    for (int k = 0; k < OUT_CH; ++k) s = fmaf(sp[k], lw[k * NUM_CLS + t], s);
    out[g * NUM_CLS + t] = s;
  }
}

extern "C" void kernel_launch(void* const* d_in, const int* in_sizes, int n_in,
                              void* d_out, int out_size, void* d_ws, size_t ws_size,
                              hipStream_t stream) {
  const float* x      = (const float*)d_in[0];
  const int*   ei     = (const int*)d_in[1];
  const int*   batch  = (const int*)d_in[2];
  const float* w1     = (const float*)d_in[4];
  const float* b1     = (const float*)d_in[5];
  const float* rel1w  = (const float*)d_in[6];
  const float* rel1b  = (const float*)d_in[7];
  const float* root1w = (const float*)d_in[8];
  const float* rel2w  = (const float*)d_in[9];
  const float* rel2b  = (const float*)d_in[10];
  const float* root2w = (const float*)d_in[11];
  const float* rel3w  = (const float*)d_in[12];
  const float* rel3b  = (const float*)d_in[13];
  const float* root3w = (const float*)d_in[14];
  const float* linw   = (const float*)d_in[15];
  const float* linb   = (const float*)d_in[16];
  const int* src = ei;
  const int* dst = ei + N_EDGES;
  float* out = (float*)d_out;

  // ---- workspace layout ----
  unsigned short* P = (unsigned short*)d_ws;            // [N,128] bf16
  unsigned short* Q = P + (size_t)N_NODES * 128;        // [N,128] bf16
  unsigned short* R = Q + (size_t)N_NODES * 128;        // [N,128] bf16
  short* WP = (short*)(R + (size_t)N_NODES * 128);
  short* w1p  = WP;                 // 128x64
  short* r1p  = w1p + 8192;         // 64x64
  short* o1p  = r1p + 4096;         // 64x64
  short* r2p  = o1p + 4096;         // 64x128
  short* o2p  = r2p + 8192;         // 64x128
  short* r3p  = o2p + 8192;         // 128x128
  short* o3p  = r3p + 16384;        // 128x128
  int* off     = (int*)(o3p + 16384);                   // N+1
  int* bcnt    = off + (N_NODES + 1);                   // NBUK
  int* bbase   = bcnt + NBUK;                           // NBUK
  int* esrc    = bbase + NBUK + 2;                      // [E]
  uint2* bbuf  = (uint2*)((char*)(esrc + N_EDGES) +
                          ((16 - (((size_t)(esrc + N_EDGES)) & 15)) & 15));

  // ---- bucketed CSR build ----
  hipMemsetAsync(bcnt, 0, NBUK * sizeof(int), stream);
  k_bucketA<<<(N_EDGES + EPB_A - 1) / EPB_A, 256, 0, stream>>>(src, dst, bcnt, bbuf);
  k_scanb<<<1, 256, 0, stream>>>(bcnt, bbase, off);
  k_bfin<<<NBUK, 256, 0, stream>>>(bcnt, bbuf, bbase, off, esrc);

  // ---- weights ----
  k_packall<<<256, 256, 0, stream>>>(w1, rel1w, root1w, rel2w, root2w, rel3w,
                                     root3w, w1p, r1p, o1p, r2p, o2p, r3p, o3p);

  const int GF = (N_NODES + 15) / 16;     // 3125 blocks, 16 nodes / 1 wave each

  // ---- pipeline ----
  k_stage1<<<GF, 64, 0, stream>>>(x, w1p, b1, P);
  k_fused<64, 64><<<GF, 64, 0, stream>>>(P, esrc, off, r1p, o1p, rel1b, R);
  k_fused<64, 128><<<GF, 64, 0, stream>>>(R, esrc, off, r2p, o2p, rel2b, Q);
  k_fused<128, 128><<<GF, 64, 0, stream>>>(Q, esrc, off, r3p, o3p, rel3b, P);
  k_poolhead<<<NUM_G, 128, 0, stream>>>(P, batch, linw, linb, out);
}

// Round 12
// 249.654 us; speedup vs baseline: 1.1338x; 1.0204x over previous
//
#include <hip/hip_runtime.h>
#include <hip/hip_bf16.h>

#define N_NODES 50000
#define N_EDGES 800000
#define IN_DIM  128
#define IN_CH   64
#define HIDDEN  64
#define OUT_CH  128
#define NUM_CLS 16
#define NUM_G   512
#define NBUK    ((N_NODES + 255) >> 8)    // 196 buckets of 256 dst nodes
#define BCAP    6144                      // mean 4082/bucket -> huge margin
#define EPB_A   4096                      // edges per pass-A block

typedef __attribute__((ext_vector_type(8))) short short8;
typedef __attribute__((ext_vector_type(4))) float f32x4;

__device__ inline float bits2f(unsigned short u) {
  unsigned x = (unsigned)u << 16;
  float f;
  __builtin_memcpy(&f, &x, 4);
  return f;
}
__device__ inline unsigned short f2bits(float v) {
  __hip_bfloat16 b = __float2bfloat16(v);   // RNE
  unsigned short s;
  __builtin_memcpy(&s, &b, 2);
  return s;
}
__device__ inline short8 zero8() {
  short8 z;
#pragma unroll
  for (int i = 0; i < 8; ++i) z[i] = 0;
  return z;
}
__device__ inline void acc2(float& a0, float& a1, unsigned v) {
  a0 += bits2f((unsigned short)v);
  a1 += bits2f((unsigned short)(v >> 16));
}
__device__ inline void accu4(float* a, uint4 v) {
  acc2(a[0], a[1], v.x); acc2(a[2], a[3], v.y);
  acc2(a[4], a[5], v.z); acc2(a[6], a[7], v.w);
}

// ============ stage1: one wave per 16 rows ============
__global__ __launch_bounds__(64) void k_stage1(
    const float* __restrict__ Ap, const short* __restrict__ Wa,
    const float* __restrict__ bias, unsigned short* __restrict__ outp) {
  constexpr int DIN = 128, DOUT = 64, KT = DIN / 32, CT = DOUT / 16;
  const int lane = threadIdx.x;
  const int m = lane & 15;
  const int q = lane >> 4;
  const int row = blockIdx.x * 16 + m;
  const bool ok = row < N_NODES;

  short8 afr[KT];
#pragma unroll
  for (int kt = 0; kt < KT; ++kt) {
    short8 f = zero8();
    if (ok) {
      const float* ap = Ap + (size_t)row * DIN + kt * 32 + q * 8;
      float4 x0 = *(const float4*)ap;
      float4 x1 = *(const float4*)(ap + 4);
      f[0] = (short)f2bits(x0.x); f[1] = (short)f2bits(x0.y);
      f[2] = (short)f2bits(x0.z); f[3] = (short)f2bits(x0.w);
      f[4] = (short)f2bits(x1.x); f[5] = (short)f2bits(x1.y);
      f[6] = (short)f2bits(x1.z); f[7] = (short)f2bits(x1.w);
    }
    afr[kt] = f;
  }
  const int rbase = blockIdx.x * 16;
#pragma unroll
  for (int ct = 0; ct < CT; ++ct) {
    f32x4 c = {0.f, 0.f, 0.f, 0.f};
#pragma unroll
    for (int kt = 0; kt < KT; ++kt) {
      short8 b = *(const short8*)(Wa + ((size_t)(kt * CT + ct) * 64 + lane) * 8);
      c = __builtin_amdgcn_mfma_f32_16x16x32_bf16(afr[kt], b, c, 0, 0, 0);
    }
    float bv = bias[ct * 16 + m];
#pragma unroll
    for (int r = 0; r < 4; ++r) {
      int ro = rbase + q * 4 + r;
      if (ro < N_NODES) outp[(size_t)ro * DOUT + ct * 16 + m] = f2bits(c[r] + bv);
    }
  }
}

// ============ fused gather + dual MFMA, one wave per 16 nodes ============
// R8-proven interleaved 2-edge loop: compiler software-pipelines the loads
// (8 uint4 in flight/lane). Do NOT batch loads manually (R10: occ 25->15%)
// and do NOT split edges across waves via LDS (R9: 46->62 us).
template <int DIN, int DOUT>
__global__ __launch_bounds__(64) void k_fused(
    const unsigned short* __restrict__ h, const int* __restrict__ esrc,
    const int* __restrict__ off, const short* __restrict__ Wa,
    const short* __restrict__ Wh, const float* __restrict__ bias,
    unsigned short* __restrict__ outp) {
  constexpr int KT = DIN / 32;
  constexpr int CT = DOUT / 16;
  const int lane = threadIdx.x;
  const int m = lane & 15;
  const int q = lane >> 4;
  const int node = blockIdx.x * 16 + m;
  const bool ok = node < N_NODES;

  float acc[KT][8];
#pragma unroll
  for (int kt = 0; kt < KT; ++kt)
#pragma unroll
    for (int j = 0; j < 8; ++j) acc[kt][j] = 0.f;

  if (ok) {
    int e = off[node], end = off[node + 1];
    const unsigned short* hq = h + q * 8;
    for (; e + 2 <= end; e += 2) {
      int s0 = esrc[e], s1 = esrc[e + 1];
      const unsigned short* r0 = hq + (size_t)s0 * DIN;
      const unsigned short* r1 = hq + (size_t)s1 * DIN;
#pragma unroll
      for (int kt = 0; kt < KT; ++kt) {
        uint4 va = *(const uint4*)(r0 + kt * 32);
        uint4 vb = *(const uint4*)(r1 + kt * 32);
        accu4(acc[kt], va);
        accu4(acc[kt], vb);
      }
    }
    if (e < end) {
      const unsigned short* r0 = hq + (size_t)esrc[e] * DIN;
#pragma unroll
      for (int kt = 0; kt < KT; ++kt)
        accu4(acc[kt], *(const uint4*)(r0 + kt * 32));
    }
  }

  short8 afr[KT], hfr[KT];
#pragma unroll
  for (int kt = 0; kt < KT; ++kt) {
    short8 f;
#pragma unroll
    for (int j = 0; j < 8; ++j) f[j] = (short)f2bits(acc[kt][j]);
    afr[kt] = f;
    hfr[kt] = ok ? *(const short8*)(h + (size_t)node * DIN + kt * 32 + q * 8)
                 : zero8();
  }

  const int rbase = blockIdx.x * 16;
#pragma unroll
  for (int ct = 0; ct < CT; ++ct) {
    f32x4 c = {0.f, 0.f, 0.f, 0.f};
#pragma unroll
    for (int kt = 0; kt < KT; ++kt) {
      short8 b = *(const short8*)(Wa + ((size_t)(kt * CT + ct) * 64 + lane) * 8);
      c = __builtin_amdgcn_mfma_f32_16x16x32_bf16(afr[kt], b, c, 0, 0, 0);
      short8 bh = *(const short8*)(Wh + ((size_t)(kt * CT + ct) * 64 + lane) * 8);
      c = __builtin_amdgcn_mfma_f32_16x16x32_bf16(hfr[kt], bh, c, 0, 0, 0);
    }
    float bv = bias[ct * 16 + m];
#pragma unroll
    for (int r = 0; r < 4; ++r) {
      int row = rbase + q * 4 + r;
      if (row < N_NODES)
        outp[(size_t)row * DOUT + ct * 16 + m] = f2bits(fmaxf(c[r] + bv, 0.f));
    }
  }
}

// ============ weight pack helper (flat index over all 7 matrices) ============
template <int DIN, int DOUT>
__device__ inline void pack1(const float* __restrict__ W, short* __restrict__ o,
                             int t) {
  constexpr int CT = DOUT / 16;
  int j = t & 7;
  int lane = (t >> 3) & 63;
  int kc = t >> 9;
  int ct = kc % CT;
  int kt = kc / CT;
  int k = kt * 32 + (lane >> 4) * 8 + j;
  int n = ct * 16 + (lane & 15);
  o[t] = (short)f2bits(W[k * DOUT + n]);
}

struct PackArgs {
  const float *w1, *r1, *o1, *r2, *o2, *r3, *o3;
  short *w1p, *r1p, *o1p, *r2p, *o2p, *r3p, *o3p;
};

__device__ inline void packflat(const PackArgs& a, int t) {
  if      (t < 8192)  pack1<128, 64>(a.w1, a.w1p, t);
  else if (t < 12288) pack1<64, 64>(a.r1, a.r1p, t - 8192);
  else if (t < 16384) pack1<64, 64>(a.o1, a.o1p, t - 12288);
  else if (t < 24576) pack1<64, 128>(a.r2, a.r2p, t - 16384);
  else if (t < 32768) pack1<64, 128>(a.o2, a.o2p, t - 24576);
  else if (t < 49152) pack1<128, 128>(a.r3, a.r3p, t - 32768);
  else if (t < 65536) pack1<128, 128>(a.o3, a.o3p, t - 49152);
}

// ================= bucketed CSR build (pass A) + weight pack =================
__global__ __launch_bounds__(256) void k_bucketA(const int* __restrict__ src,
    const int* __restrict__ dst, int* __restrict__ bcnt, uint2* __restrict__ bbuf,
    PackArgs pk) {
  __shared__ int hist[NBUK], sbase[NBUK], lcur[NBUK];
  const int t = threadIdx.x;

  // fold weight packing in: 196 blocks x 256 thr = 50176 threads, 65536 items
  {
    int g0 = blockIdx.x * 256 + t;
    packflat(pk, g0);
    packflat(pk, g0 + 50176);
  }

  for (int i = t; i < NBUK; i += 256) { hist[i] = 0; lcur[i] = 0; }
  __syncthreads();
  const int e0 = blockIdx.x * EPB_A;
  int s_[16], d_[16];
  int cnt = 0;
#pragma unroll
  for (int k = 0; k < 16; ++k) {
    int e = e0 + k * 256 + t;
    if (e < N_EDGES) {
      s_[cnt] = src[e]; d_[cnt] = dst[e];
      atomicAdd(&hist[d_[cnt] >> 8], 1);
      cnt++;
    }
  }
  __syncthreads();
  for (int i = t; i < NBUK; i += 256) sbase[i] = atomicAdd(&bcnt[i], hist[i]);
  __syncthreads();
  for (int k = 0; k < cnt; ++k) {
    int b = d_[k] >> 8;
    int pos = sbase[b] + atomicAdd(&lcur[b], 1);
    if (pos < BCAP) bbuf[(size_t)b * BCAP + pos] = make_uint2((unsigned)s_[k], (unsigned)d_[k]);
  }
}

// per-bucket finalize: redundant bucket-base scan (LDS) + degree hist +
// intra-bucket scan -> off[node]; then scatter esrc. Replaces scanb+bfin.
__global__ __launch_bounds__(256) void k_bfin(const int* __restrict__ bcnt,
    const uint2* __restrict__ bbuf, int* __restrict__ off,
    int* __restrict__ esrc) {
  __shared__ int cnt[256], s[256], soff[256];
  const int b = blockIdx.x;
  const int t = threadIdx.x;

  // bucket-base scan, redundantly per block (196 ints -> trivial)
  int bv0 = (t < NBUK) ? min(bcnt[t], BCAP) : 0;
  s[t] = bv0;
  __syncthreads();
  for (int st = 1; st < 256; st <<= 1) {
    int v = (t >= st) ? s[t - st] : 0;
    __syncthreads();
    s[t] += v;
    __syncthreads();
  }
  __shared__ int bbase_s;
  if (t == b) bbase_s = s[t] - bv0;                 // exclusive prefix for bucket b
  if (b == 0 && t == NBUK - 1) off[N_NODES] = s[t]; // total edge count
  __syncthreads();
  const int bb = bbase_s;

  cnt[t] = 0;
  __syncthreads();
  int n = min(bcnt[b], BCAP);
  for (int i = t; i < n; i += 256)
    atomicAdd(&cnt[bbuf[(size_t)b * BCAP + i].y & 255], 1);
  __syncthreads();
  int v0 = cnt[t];
  s[t] = v0;
  __syncthreads();
  for (int st = 1; st < 256; st <<= 1) {
    int v = (t >= st) ? s[t - st] : 0;
    __syncthreads();
    s[t] += v;
    __syncthreads();
  }
  int myoff = bb + s[t] - v0;
  int node = b * 256 + t;
  if (node < N_NODES) off[node] = myoff;
  soff[t] = myoff;
  cnt[t] = 0;            // reuse as per-node cursor
  __syncthreads();
  for (int i = t; i < n; i += 256) {
    uint2 p = bbuf[(size_t)b * BCAP + i];
    int l = p.y & 255;
    int r = atomicAdd(&cnt[l], 1);
    esrc[soff[l] + r] = (int)p.x;
  }
}

// ================= fused pool + head =================
__device__ inline int lbound(const int* __restrict__ a, int n, int v) {
  int lo = 0, hi = n;
  while (lo < hi) {
    int m = (lo + hi) >> 1;
    if (a[m] < v) lo = m + 1; else hi = m;
  }
  return lo;
}

__global__ __launch_bounds__(128) void k_poolhead(const unsigned short* __restrict__ h3,
    const int* __restrict__ batch, const float* __restrict__ lw,
    const float* __restrict__ lb, float* __restrict__ out) {
  __shared__ float sp[128];
  int g = blockIdx.x;
  int t = threadIdx.x;
  int lo = lbound(batch, N_NODES, g);
  int hi = lbound(batch, N_NODES, g + 1);
  float a0 = 0.f, a1 = 0.f, a2 = 0.f, a3 = 0.f;
  int r = lo;
  for (; r + 4 <= hi; r += 4) {
    a0 += bits2f(h3[(size_t)(r + 0) * OUT_CH + t]);
    a1 += bits2f(h3[(size_t)(r + 1) * OUT_CH + t]);
    a2 += bits2f(h3[(size_t)(r + 2) * OUT_CH + t]);
    a3 += bits2f(h3[(size_t)(r + 3) * OUT_CH + t]);
  }
  for (; r < hi; ++r) a0 += bits2f(h3[(size_t)r * OUT_CH + t]);
  float inv = (hi > lo) ? 1.f / (float)(hi - lo) : 0.f;
  sp[t] = ((a0 + a1) + (a2 + a3)) * inv;
  __syncthreads();
  if (t < NUM_CLS) {
    float s = lb[t];
#pragma unroll
    for (int k = 0; k < OUT_CH; ++k) s = fmaf(sp[k], lw[k * NUM_CLS + t], s);
    out[g * NUM_CLS + t] = s;
  }
}

extern "C" void kernel_launch(void* const* d_in, const int* in_sizes, int n_in,
                              void* d_out, int out_size, void* d_ws, size_t ws_size,
                              hipStream_t stream) {
  const float* x      = (const float*)d_in[0];
  const int*   ei     = (const int*)d_in[1];
  const int*   batch  = (const int*)d_in[2];
  const float* w1     = (const float*)d_in[4];
  const float* b1     = (const float*)d_in[5];
  const float* rel1w  = (const float*)d_in[6];
  const float* rel1b  = (const float*)d_in[7];
  const float* root1w = (const float*)d_in[8];
  const float* rel2w  = (const float*)d_in[9];
  const float* rel2b  = (const float*)d_in[10];
  const float* root2w = (const float*)d_in[11];
  const float* rel3w  = (const float*)d_in[12];
  const float* rel3b  = (const float*)d_in[13];
  const float* root3w = (const float*)d_in[14];
  const float* linw   = (const float*)d_in[15];
  const float* linb   = (const float*)d_in[16];
  const int* src = ei;
  const int* dst = ei + N_EDGES;
  float* out = (float*)d_out;

  // ---- workspace layout ----
  unsigned short* P = (unsigned short*)d_ws;            // [N,128] bf16
  unsigned short* Q = P + (size_t)N_NODES * 128;        // [N,128] bf16
  unsigned short* R = Q + (size_t)N_NODES * 128;        // [N,128] bf16
  short* WP = (short*)(R + (size_t)N_NODES * 128);
  short* w1p  = WP;                 // 128x64
  short* r1p  = w1p + 8192;         // 64x64
  short* o1p  = r1p + 4096;         // 64x64
  short* r2p  = o1p + 4096;         // 64x128
  short* o2p  = r2p + 8192;         // 64x128
  short* r3p  = o2p + 8192;         // 128x128
  short* o3p  = r3p + 16384;        // 128x128
  int* off     = (int*)(o3p + 16384);                   // N+1
  int* bcnt    = off + (N_NODES + 1);                   // NBUK
  int* esrc    = bcnt + NBUK + 3;                       // [E]
  uint2* bbuf  = (uint2*)((char*)(esrc + N_EDGES) +
                          ((16 - (((size_t)(esrc + N_EDGES)) & 15)) & 15));

  PackArgs pk = {w1, rel1w, root1w, rel2w, root2w, rel3w, root3w,
                 w1p, r1p, o1p, r2p, o2p, r3p, o3p};

  // ---- bucketed CSR build + weight pack (3 dispatches incl. memset) ----
  hipMemsetAsync(bcnt, 0, NBUK * sizeof(int), stream);
  k_bucketA<<<(N_EDGES + EPB_A - 1) / EPB_A, 256, 0, stream>>>(src, dst, bcnt,
                                                               bbuf, pk);
  k_bfin<<<NBUK, 256, 0, stream>>>(bcnt, bbuf, off, esrc);

  const int GF = (N_NODES + 15) / 16;     // 3125 blocks, 16 nodes / 1 wave each

  // ---- pipeline ----
  k_stage1<<<GF, 64, 0, stream>>>(x, w1p, b1, P);
  k_fused<64, 64><<<GF, 64, 0, stream>>>(P, esrc, off, r1p, o1p, rel1b, R);
  k_fused<64, 128><<<GF, 64, 0, stream>>>(R, esrc, off, r2p, o2p, rel2b, Q);
  k_fused<128, 128><<<GF, 64, 0, stream>>>(Q, esrc, off, r3p, o3p, rel3b, P);
  k_poolhead<<<NUM_G, 128, 0, stream>>>(P, batch, linw, linb, out);
}